// Round 8
// baseline (535.259 us; speedup 1.0000x reference)
//
#include <hip/hip_runtime.h>
#include <hip/hip_bf16.h>

#define N_TOK 32768
#define DIM   192
#define HID   384
#define NEXP  8
#define EPSV 2.220446049250313e-16f

typedef __attribute__((ext_vector_type(8))) short short8;
typedef __attribute__((ext_vector_type(4))) float f32x4;

static __device__ __forceinline__ short f2bf(float f) {
    union { __hip_bfloat16 h; short s; } u;
    u.h = __float2bfloat16(f);
    return u.s;
}

typedef const __attribute__((address_space(1))) void* gptr_t;
typedef __attribute__((address_space(3))) void* lptr_t;
#define GLOAD_LDS16(g, l) \
    __builtin_amdgcn_global_load_lds((gptr_t)(const void*)(g), (lptr_t)(void*)(l), 16, 0, 0)

// ---------------------------------------------------------------------------
// Gating, 4 lanes per token: logits = [x,emb]@w_gate (fp32, must match ref
// selection); top-2; softmax; scatter to expert lists + inverse map.
// ---------------------------------------------------------------------------
__global__ __launch_bounds__(256) void gate_kernel(
    const float* __restrict__ x, const float* __restrict__ emb,
    const float* __restrict__ wg,
    int* __restrict__ counts, int* __restrict__ toks, float* __restrict__ gates,
    int* __restrict__ inv)
{
    __shared__ float wgs[2 * DIM * NEXP];   // 12 KB
    __shared__ int cnt[NEXP];
    __shared__ int base[NEXP];
    int tid = threadIdx.x;
    for (int i = tid; i < 2 * DIM * NEXP; i += 256) wgs[i] = wg[i];
    if (tid < NEXP) cnt[tid] = 0;
    __syncthreads();

    int t = blockIdx.x * 64 + (tid >> 2);
    int q = tid & 3;
    const float* src = ((q < 2) ? x : emb) + (size_t)t * DIM + (q & 1) * 96;

    float acc[NEXP];
#pragma unroll
    for (int e = 0; e < NEXP; ++e) acc[e] = 0.f;

#pragma unroll
    for (int i = 0; i < 12; ++i) {           // 8 concat-dims per iter, fully unrolled
        float4 v0 = reinterpret_cast<const float4*>(src)[2 * i];
        float4 v1 = reinterpret_cast<const float4*>(src)[2 * i + 1];
        const float* wr = &wgs[(q * 96 + i * 8) * NEXP];
        float vs[8] = {v0.x, v0.y, v0.z, v0.w, v1.x, v1.y, v1.z, v1.w};
#pragma unroll
        for (int u = 0; u < 8; ++u)
#pragma unroll
            for (int e = 0; e < NEXP; ++e)
                acc[e] += vs[u] * wr[u * NEXP + e];
    }

#pragma unroll
    for (int e = 0; e < NEXP; ++e) {
        acc[e] += __shfl_xor(acc[e], 1);
        acc[e] += __shfl_xor(acc[e], 2);
    }

    int i1 = 0, i2 = -1, p1 = 0, p2 = 0;
    float g1 = 0.f, g2 = 0.f;
    if (q == 0) {
        float l1 = acc[0];
#pragma unroll
        for (int e = 1; e < NEXP; ++e) { if (acc[e] > l1) { l1 = acc[e]; i1 = e; } }
        float l2 = -1e30f;
#pragma unroll
        for (int e = 0; e < NEXP; ++e) { if (e != i1 && acc[e] > l2) { l2 = acc[e]; i2 = e; } }
        g1 = 1.f / (1.f + expf(l2 - l1));
        g2 = 1.f - g1;
        p1 = atomicAdd(&cnt[i1], 1);
        p2 = atomicAdd(&cnt[i2], 1);
    }
    __syncthreads();
    if (tid < NEXP) base[tid] = atomicAdd(&counts[tid], cnt[tid]);
    __syncthreads();
    if (q == 0) {
        int o1 = base[i1] + p1;
        int o2 = base[i2] + p2;
        toks[i1 * N_TOK + o1]  = t;
        gates[i1 * N_TOK + o1] = g1;
        toks[i2 * N_TOK + o2]  = t;
        gates[i2 * N_TOK + o2] = g2;
        inv[2 * t]     = (i1 << 17) | o1;
        inv[2 * t + 1] = (i2 << 17) | o2;
    }
}

// ---------------------------------------------------------------------------
// Pack:
//  pb1[e][jh][kt(6)][jtl(12)][lane][8]  : W1 B-fragments (jh halves HID)
//  pa2[e][oh][kt(12)][mtl(6)][lane][8]  : W2^T A-fragments (oh halves DIM out)
//    A-frag: lane l elem t -> out = oh*96+mtl*16+(l&15), hid = kt*32+(l>>4)*8+t
// One thread = one coalesced 16B fragment write.
// ---------------------------------------------------------------------------
__global__ __launch_bounds__(256) void pack_kernel(
    const float* __restrict__ w1, const float* __restrict__ w2,
    short* __restrict__ pb1, short* __restrict__ pa2)
{
    const int Q1 = NEXP * 2 * 6 * 12 * 64;   // 73728
    const int Q2 = NEXP * 2 * 12 * 6 * 64;   // 73728
    int gid = blockIdx.x * 256 + threadIdx.x;
    if (gid < Q1) {
        int lane = gid & 63;
        int r = gid >> 6;
        int jtl = r % 12; r /= 12;
        int kt  = r % 6;  r /= 6;
        int jh  = r & 1;  int e = r >> 1;
        int j  = jh * 192 + jtl * 16 + (lane & 15);
        int k0 = kt * 32 + (lane >> 4) * 8;
        const float* src = w1 + ((size_t)e * DIM + k0) * HID + j;
        short8 s;
#pragma unroll
        for (int t = 0; t < 8; ++t) s[t] = f2bf(src[t * HID]);
        *reinterpret_cast<short8*>(pb1 + (size_t)gid * 8) = s;
    } else if (gid < Q1 + Q2) {
        int g2 = gid - Q1;
        int lane = g2 & 63;
        int r = g2 >> 6;
        int mtl = r % 6;  r /= 6;
        int kt  = r % 12; r /= 12;
        int oh  = r & 1;  int e = r >> 1;
        int out = oh * 96 + mtl * 16 + (lane & 15);
        int k0  = kt * 32 + (lane >> 4) * 8;
        const float* src = w2 + ((size_t)e * HID + k0) * DIM + out;
        short8 s;
#pragma unroll
        for (int t = 0; t < 8; ++t) s[t] = f2bf(src[t * DIM]);
        *reinterpret_cast<short8*>(pa2 + (size_t)g2 * 8) = s;
    }
}

// ---------------------------------------------------------------------------
// Pass 1: Hp[gbase+r][jh*192:+192] = gelu(x[tok(r)] @ W1[e][:,jh] + b1)
// Persistent 72KB LDS (staged once), 8 waves free-run, NO main-loop barriers.
// grid 512: bid = rep(32)*16 + jh*8 + e ; 2 blocks/CU, 16 waves/CU.
// ---------------------------------------------------------------------------
__global__ __launch_bounds__(512, 4) void hp_kernel(
    const float* __restrict__ x,
    const short* __restrict__ pb1, const float* __restrict__ b1,
    const int* __restrict__ counts, const int* __restrict__ toks,
    char* __restrict__ Hp)
{
    int bid = blockIdx.x;
    int e   = bid & 7;
    int jh  = (bid >> 3) & 1;
    int rep = bid >> 4;
    int cnt = counts[e];
    int ntiles = (cnt + 15) >> 4;
    int gbase = 0;
#pragma unroll
    for (int i = 0; i < NEXP; ++i) gbase += (i < e) ? counts[i] : 0;

    __shared__ __align__(16) char wlds[73728];
    int tid = threadIdx.x;
    const char* wsrc = (const char*)pb1 + (size_t)(e * 2 + jh) * 73728;
#pragma unroll
    for (int i = 0; i < 9; ++i)
        GLOAD_LDS16(wsrc + i * 8192 + tid * 16, wlds + i * 8192 + tid * 16);

    int wv = tid >> 6, lane = tid & 63;
    int lrow = lane & 15, lgrp = lane >> 4;
    const int* tl = toks + e * N_TOK;
    const float* b1base = b1 + e * HID + jh * 192;
    float b1j[12];
#pragma unroll
    for (int jt = 0; jt < 12; ++jt) b1j[jt] = b1base[jt * 16 + lrow];

    int L  = (ntiles + 31) >> 5;
    int t0 = rep * L;
    int t1 = min(t0 + L, ntiles);
    __syncthreads();   // stage drained (syncthreads waits vmcnt)

    for (int t = t0 + wv; t < t1; t += 8) {
        int base = t * 16;
        int tok = tl[min(base + lrow, cnt - 1)];
        const char* xr = (const char*)x + (size_t)tok * 768 + lgrp * 32;
        short8 a[6];
#pragma unroll
        for (int kt = 0; kt < 6; ++kt) {
            float4 v0 = *(const float4*)(xr + kt * 128);
            float4 v1 = *(const float4*)(xr + kt * 128 + 16);
            short8 s;
            s[0] = f2bf(v0.x); s[1] = f2bf(v0.y); s[2] = f2bf(v0.z); s[3] = f2bf(v0.w);
            s[4] = f2bf(v1.x); s[5] = f2bf(v1.y); s[6] = f2bf(v1.z); s[7] = f2bf(v1.w);
            a[kt] = s;
        }

        f32x4 acc[12];
#pragma unroll
        for (int j = 0; j < 12; ++j) acc[j] = (f32x4){0.f, 0.f, 0.f, 0.f};
#pragma unroll
        for (int kt = 0; kt < 6; ++kt)
#pragma unroll
            for (int jt = 0; jt < 12; ++jt) {
                short8 bb = *(const short8*)(wlds + ((kt * 12 + jt) * 64 + lane) * 16);
                acc[jt] = __builtin_amdgcn_mfma_f32_16x16x32_bf16(a[kt], bb, acc[jt], 0, 0, 0);
            }

#pragma unroll
        for (int rr = 0; rr < 4; ++rr) {
            int r = base + lgrp * 4 + rr;
            if (r < cnt) {
                char* hrow = Hp + (size_t)(gbase + r) * 768 + jh * 384;
#pragma unroll
                for (int jt = 0; jt < 12; ++jt) {
                    float h = acc[jt][rr] + b1j[jt];
                    float g = 0.5f * h * (1.f + erff(h * 0.70710678118654752f));
                    *(short*)(hrow + (jt * 16 + lrow) * 2) = f2bf(g);
                }
            }
        }
    }
}

// ---------------------------------------------------------------------------
// Pass 2 (primary): slot[gbase+r][oh*96:+96] = gate * exp(y^T) with
// y^T = W2^T @ H^T : A = W2^T frags (LDS-persistent), B = H rows (contig 16B).
// D layout: col = token-in-tile, row = out -> per-lane float4 stores.
// grid 512: bid = rep(32)*16 + oh*8 + e
// ---------------------------------------------------------------------------
__global__ __launch_bounds__(512, 4) void yp_kernel(
    const char* __restrict__ Hp,
    const short* __restrict__ pa2, const float* __restrict__ b2,
    const int* __restrict__ counts, const float* __restrict__ gates,
    float* __restrict__ slot)
{
    int bid = blockIdx.x;
    int e   = bid & 7;
    int oh  = (bid >> 3) & 1;
    int rep = bid >> 4;
    int cnt = counts[e];
    int ntiles = (cnt + 15) >> 4;
    int gbase = 0;
#pragma unroll
    for (int i = 0; i < NEXP; ++i) gbase += (i < e) ? counts[i] : 0;

    __shared__ __align__(16) char wlds[73728];
    int tid = threadIdx.x;
    const char* wsrc = (const char*)pa2 + (size_t)(e * 2 + oh) * 73728;
#pragma unroll
    for (int i = 0; i < 9; ++i)
        GLOAD_LDS16(wsrc + i * 8192 + tid * 16, wlds + i * 8192 + tid * 16);

    int wv = tid >> 6, lane = tid & 63;
    int lrow = lane & 15, lgrp = lane >> 4;
    const float* gl = gates + e * N_TOK;
    f32x4 b2v[6];
#pragma unroll
    for (int m = 0; m < 6; ++m)
        b2v[m] = *(const f32x4*)(b2 + e * DIM + oh * 96 + m * 16 + lgrp * 4);

    int L  = (ntiles + 31) >> 5;
    int t0 = rep * L;
    int t1 = min(t0 + L, ntiles);
    __syncthreads();

    for (int t = t0 + wv; t < t1; t += 8) {
        int base = t * 16;
        int nrow = min(base + lrow, cnt - 1);          // token row for B-frag col
        const char* hr = Hp + (size_t)(gbase + nrow) * 768 + lgrp * 16;
        short8 bfr[12];
#pragma unroll
        for (int kt = 0; kt < 12; ++kt) bfr[kt] = *(const short8*)(hr + kt * 64);

        f32x4 acc[6];
#pragma unroll
        for (int m = 0; m < 6; ++m) acc[m] = (f32x4){0.f, 0.f, 0.f, 0.f};
#pragma unroll
        for (int kt = 0; kt < 12; ++kt)
#pragma unroll
            for (int m = 0; m < 6; ++m) {
                short8 aa = *(const short8*)(wlds + ((kt * 6 + m) * 64 + lane) * 16);
                acc[m] = __builtin_amdgcn_mfma_f32_16x16x32_bf16(aa, bfr[kt], acc[m], 0, 0, 0);
            }

        int r = base + lrow;                            // this lane's token row
        if (r < cnt) {
            float g = gl[r];
            float* srow = slot + (size_t)(gbase + r) * DIM + oh * 96;
#pragma unroll
            for (int m = 0; m < 6; ++m) {
                float4 o;
                o.x = g * expf(acc[m][0] + b2v[m][0]);
                o.y = g * expf(acc[m][1] + b2v[m][1]);
                o.z = g * expf(acc[m][2] + b2v[m][2]);
                o.w = g * expf(acc[m][3] + b2v[m][3]);
                *(float4*)(srow + m * 16 + lgrp * 4) = o;
            }
        }
    }
}

// ---------------------------------------------------------------------------
// Pass 2 (fallback, small ws): full-out W2^T streamed from global, fp32 result
// written IN PLACE over the wave's own Hp rows (read-before-write, same wave).
// grid 512: bid = rep(64)*8 + e
// ---------------------------------------------------------------------------
__global__ __launch_bounds__(512) void yp_global_kernel(
    char* __restrict__ Hp,
    const short* __restrict__ pa2, const float* __restrict__ b2,
    const int* __restrict__ counts, const float* __restrict__ gates)
{
    int bid = blockIdx.x;
    int e   = bid & 7;
    int rep = bid >> 3;
    int cnt = counts[e];
    int ntiles = (cnt + 15) >> 4;
    int gbase = 0;
#pragma unroll
    for (int i = 0; i < NEXP; ++i) gbase += (i < e) ? counts[i] : 0;

    int tid = threadIdx.x;
    int wv = tid >> 6, lane = tid & 63;
    int lrow = lane & 15, lgrp = lane >> 4;
    const float* gl = gates + e * N_TOK;
    const short8* wbase = (const short8*)(pa2 + (size_t)e * 2 * 36864) + lane;

    f32x4 b2v[12];
#pragma unroll
    for (int m = 0; m < 12; ++m)
        b2v[m] = *(const f32x4*)(b2 + e * DIM + m * 16 + lgrp * 4);

    int L  = (ntiles + 63) >> 6;
    int t0 = rep * L;
    int t1 = min(t0 + L, ntiles);

    for (int t = t0 + wv; t < t1; t += 8) {
        int base = t * 16;
        int nrow = min(base + lrow, cnt - 1);
        const char* hr = Hp + (size_t)(gbase + nrow) * 768 + lgrp * 16;
        short8 bfr[12];
#pragma unroll
        for (int kt = 0; kt < 12; ++kt) bfr[kt] = *(const short8*)(hr + kt * 64);

        f32x4 acc[12];
#pragma unroll
        for (int m = 0; m < 12; ++m) acc[m] = (f32x4){0.f, 0.f, 0.f, 0.f};
#pragma unroll
        for (int kt = 0; kt < 12; ++kt)
#pragma unroll
            for (int m = 0; m < 12; ++m) {
                // pa2 layout: [e][oh][kt][mtl(6)][lane][8]; m = oh*6+mtl
                short8 aa = wbase[(((m / 6) * 12 + kt) * 6 + (m % 6)) * 64];
                acc[m] = __builtin_amdgcn_mfma_f32_16x16x32_bf16(aa, bfr[kt], acc[m], 0, 0, 0);
            }

        int r = base + lrow;
        if (r < cnt) {
            float g = gl[r];
            float* srow = (float*)(Hp + (size_t)(gbase + r) * 768);
#pragma unroll
            for (int m = 0; m < 12; ++m) {
                float4 o;
                o.x = g * expf(acc[m][0] + b2v[m][0]);
                o.y = g * expf(acc[m][1] + b2v[m][1]);
                o.z = g * expf(acc[m][2] + b2v[m][2]);
                o.w = g * expf(acc[m][3] + b2v[m][3]);
                *(float4*)(srow + m * 16 + lgrp * 4) = o;
            }
        }
    }
}

// ---------------------------------------------------------------------------
// out[t][:] = log(slot[g1(t)][:] + slot[g2(t)][:])
// ---------------------------------------------------------------------------
__global__ __launch_bounds__(256) void combine_kernel(
    const float* __restrict__ slot, const int* __restrict__ inv,
    const int* __restrict__ counts, float* __restrict__ out)
{
    __shared__ int rb[NEXP];
    int tid = threadIdx.x;
    if (tid < NEXP) {
        int s = 0;
        for (int i = 0; i < tid; ++i) s += counts[i];
        rb[tid] = s;
    }
    __syncthreads();

    int gid = blockIdx.x * 256 + tid;        // over N_TOK*48
    int t = gid / 48, q = gid - t * 48;
    int v1 = inv[2 * t], v2 = inv[2 * t + 1];
    int g1 = rb[v1 >> 17] + (v1 & 0x1FFFF);
    int g2 = rb[v2 >> 17] + (v2 & 0x1FFFF);
    float4 a = *(const float4*)(slot + (size_t)g1 * DIM + q * 4);
    float4 b = *(const float4*)(slot + (size_t)g2 * DIM + q * 4);
    float4 o;
    float c;
    c = a.x + b.x; o.x = logf(c == 0.f ? EPSV : c);
    c = a.y + b.y; o.y = logf(c == 0.f ? EPSV : c);
    c = a.z + b.z; o.z = logf(c == 0.f ? EPSV : c);
    c = a.w + b.w; o.w = logf(c == 0.f ? EPSV : c);
    *reinterpret_cast<float4*>(out + (size_t)t * DIM + q * 4) = o;
}

// ---------------------------------------------------------------------------
extern "C" void kernel_launch(void* const* d_in, const int* in_sizes, int n_in,
                              void* d_out, int out_size, void* d_ws, size_t ws_size,
                              hipStream_t stream) {
    const float* x   = (const float*)d_in[0];
    const float* emb = (const float*)d_in[1];
    const float* wg  = (const float*)d_in[2];
    const float* w1  = (const float*)d_in[3];
    const float* b1  = (const float*)d_in[4];
    const float* w2  = (const float*)d_in[5];
    const float* b2  = (const float*)d_in[6];
    float* out = (float*)d_out;

    char* ws = (char*)d_ws;
    size_t off = 0;
    auto alloc = [&](size_t n) { size_t p = off; off = (off + n + 255) & ~(size_t)255; return p; };
    int*   counts = (int*)  (ws + alloc(256));
    int*   toks   = (int*)  (ws + alloc((size_t)NEXP * N_TOK * 4));
    float* gates  = (float*)(ws + alloc((size_t)NEXP * N_TOK * 4));
    int*   inv    = (int*)  (ws + alloc((size_t)2 * N_TOK * 4));
    short* pb1    = (short*)(ws + alloc((size_t)NEXP * DIM * HID * 2));
    short* pa2    = (short*)(ws + alloc((size_t)NEXP * HID * DIM * 2));
    char*  Hp     = (char*) (ws + alloc((size_t)2 * N_TOK * 768));   // bf16 H rows / fp32 slot rows
    size_t sloff  = alloc((size_t)2 * N_TOK * DIM * 4);              // separate fp32 slot
    float* slot   = (float*)(ws + sloff);
    bool split_y  = (ws_size >= off);

    hipMemsetAsync(counts, 0, NEXP * sizeof(int), stream);

    pack_kernel<<<(2 * 73728) / 256, 256, 0, stream>>>(w1, w2, pb1, pa2);
    gate_kernel<<<N_TOK / 64, 256, 0, stream>>>(x, emb, wg, counts, toks, gates, inv);
    hp_kernel<<<512, 512, 0, stream>>>(x, pb1, b1, counts, toks, Hp);

    if (split_y) {
        yp_kernel<<<512, 512, 0, stream>>>(Hp, pa2, b2, counts, gates, slot);
        combine_kernel<<<(N_TOK * 48) / 256, 256, 0, stream>>>(slot, inv, counts, out);
    } else {
        yp_global_kernel<<<512, 512, 0, stream>>>(Hp, pa2, b2, counts, gates);
        combine_kernel<<<(N_TOK * 48) / 256, 256, 0, stream>>>((const float*)Hp, inv, counts, out);
    }
}

// Round 9
// 322.950 us; speedup vs baseline: 1.6574x; 1.6574x over previous
//
#include <hip/hip_runtime.h>
#include <hip/hip_bf16.h>

#define N_TOK 32768
#define DIM   192
#define HID   384
#define NEXP  8
#define EPSV 2.220446049250313e-16f

typedef __attribute__((ext_vector_type(8))) short short8;
typedef __attribute__((ext_vector_type(4))) float f32x4;

static __device__ __forceinline__ short f2bf(float f) {
    union { __hip_bfloat16 h; short s; } u;
    u.h = __float2bfloat16(f);
    return u.s;
}

typedef const __attribute__((address_space(1))) void* gptr_t;
typedef __attribute__((address_space(3))) void* lptr_t;
#define GLOAD_LDS16(g, l) \
    __builtin_amdgcn_global_load_lds((gptr_t)(const void*)(g), (lptr_t)(void*)(l), 16, 0, 0)

// ---------------------------------------------------------------------------
// Gating, 4 lanes per token: logits = [x,emb]@w_gate (fp32, must match ref
// selection); top-2; softmax; scatter to expert lists + inverse map.
// ---------------------------------------------------------------------------
__global__ __launch_bounds__(256) void gate_kernel(
    const float* __restrict__ x, const float* __restrict__ emb,
    const float* __restrict__ wg,
    int* __restrict__ counts, int* __restrict__ toks, float* __restrict__ gates,
    int* __restrict__ inv)
{
    __shared__ float wgs[2 * DIM * NEXP];   // 12 KB
    __shared__ int cnt[NEXP];
    __shared__ int base[NEXP];
    int tid = threadIdx.x;
    for (int i = tid; i < 2 * DIM * NEXP; i += 256) wgs[i] = wg[i];
    if (tid < NEXP) cnt[tid] = 0;
    __syncthreads();

    int t = blockIdx.x * 64 + (tid >> 2);
    int q = tid & 3;
    const float* src = ((q < 2) ? x : emb) + (size_t)t * DIM + (q & 1) * 96;

    float acc[NEXP];
#pragma unroll
    for (int e = 0; e < NEXP; ++e) acc[e] = 0.f;

#pragma unroll
    for (int i = 0; i < 12; ++i) {           // 8 concat-dims per iter, fully unrolled
        float4 v0 = reinterpret_cast<const float4*>(src)[2 * i];
        float4 v1 = reinterpret_cast<const float4*>(src)[2 * i + 1];
        const float* wr = &wgs[(q * 96 + i * 8) * NEXP];
        float vs[8] = {v0.x, v0.y, v0.z, v0.w, v1.x, v1.y, v1.z, v1.w};
#pragma unroll
        for (int u = 0; u < 8; ++u)
#pragma unroll
            for (int e = 0; e < NEXP; ++e)
                acc[e] += vs[u] * wr[u * NEXP + e];
    }

#pragma unroll
    for (int e = 0; e < NEXP; ++e) {
        acc[e] += __shfl_xor(acc[e], 1);
        acc[e] += __shfl_xor(acc[e], 2);
    }

    int i1 = 0, i2 = -1, p1 = 0, p2 = 0;
    float g1 = 0.f, g2 = 0.f;
    if (q == 0) {
        float l1 = acc[0];
#pragma unroll
        for (int e = 1; e < NEXP; ++e) { if (acc[e] > l1) { l1 = acc[e]; i1 = e; } }
        float l2 = -1e30f;
#pragma unroll
        for (int e = 0; e < NEXP; ++e) { if (e != i1 && acc[e] > l2) { l2 = acc[e]; i2 = e; } }
        g1 = 1.f / (1.f + expf(l2 - l1));
        g2 = 1.f - g1;
        p1 = atomicAdd(&cnt[i1], 1);
        p2 = atomicAdd(&cnt[i2], 1);
    }
    __syncthreads();
    if (tid < NEXP) base[tid] = atomicAdd(&counts[tid], cnt[tid]);
    __syncthreads();
    if (q == 0) {
        int o1 = base[i1] + p1;
        int o2 = base[i2] + p2;
        toks[i1 * N_TOK + o1]  = t;
        gates[i1 * N_TOK + o1] = g1;
        toks[i2 * N_TOK + o2]  = t;
        gates[i2 * N_TOK + o2] = g2;
        inv[2 * t]     = (i1 << 17) | o1;
        inv[2 * t + 1] = (i2 << 17) | o2;
    }
}

// ---------------------------------------------------------------------------
// Pack:
//  pb1[e][jh][kt(6)][jtl(12)][lane][8]  : W1 B-fragments (jh halves HID)
//  pa2[e][oh][kt(12)][mtl(6)][lane][8]  : W2^T A-fragments (oh halves DIM out)
//    A-frag: lane l elem t -> out = oh*96+mtl*16+(l&15), hid = kt*32+(l>>4)*8+t
// One thread = one coalesced 16B fragment write.
// ---------------------------------------------------------------------------
__global__ __launch_bounds__(256) void pack_kernel(
    const float* __restrict__ w1, const float* __restrict__ w2,
    short* __restrict__ pb1, short* __restrict__ pa2)
{
    const int Q1 = NEXP * 2 * 6 * 12 * 64;   // 73728
    const int Q2 = NEXP * 2 * 12 * 6 * 64;   // 73728
    int gid = blockIdx.x * 256 + threadIdx.x;
    if (gid < Q1) {
        int lane = gid & 63;
        int r = gid >> 6;
        int jtl = r % 12; r /= 12;
        int kt  = r % 6;  r /= 6;
        int jh  = r & 1;  int e = r >> 1;
        int j  = jh * 192 + jtl * 16 + (lane & 15);
        int k0 = kt * 32 + (lane >> 4) * 8;
        const float* src = w1 + ((size_t)e * DIM + k0) * HID + j;
        short8 s;
#pragma unroll
        for (int t = 0; t < 8; ++t) s[t] = f2bf(src[t * HID]);
        *reinterpret_cast<short8*>(pb1 + (size_t)gid * 8) = s;
    } else if (gid < Q1 + Q2) {
        int g2 = gid - Q1;
        int lane = g2 & 63;
        int r = g2 >> 6;
        int mtl = r % 6;  r /= 6;
        int kt  = r % 12; r /= 12;
        int oh  = r & 1;  int e = r >> 1;
        int out = oh * 96 + mtl * 16 + (lane & 15);
        int k0  = kt * 32 + (lane >> 4) * 8;
        const float* src = w2 + ((size_t)e * HID + k0) * DIM + out;
        short8 s;
#pragma unroll
        for (int t = 0; t < 8; ++t) s[t] = f2bf(src[t * DIM]);
        *reinterpret_cast<short8*>(pa2 + (size_t)g2 * 8) = s;
    }
}

// ---------------------------------------------------------------------------
// Pass 1: Hp[gbase+r][jh*192:+192] = gelu(x[tok(r)] @ W1[e][:,jh] + b1)
// Persistent 72KB LDS (staged once), 8 waves free-run, NO main-loop barriers.
// grid 512: bid = rep(32)*16 + jh*8 + e ; launch_bounds floor only (keep VGPR
// natural ~116 -> 4 waves/SIMD, 2 blocks/CU at runtime).
// ---------------------------------------------------------------------------
__global__ __launch_bounds__(512, 2) void hp_kernel(
    const float* __restrict__ x,
    const short* __restrict__ pb1, const float* __restrict__ b1,
    const int* __restrict__ counts, const int* __restrict__ toks,
    char* __restrict__ Hp)
{
    int bid = blockIdx.x;
    int e   = bid & 7;
    int jh  = (bid >> 3) & 1;
    int rep = bid >> 4;
    int cnt = counts[e];
    int ntiles = (cnt + 15) >> 4;
    int gbase = 0;
#pragma unroll
    for (int i = 0; i < NEXP; ++i) gbase += (i < e) ? counts[i] : 0;

    __shared__ __align__(16) char wlds[73728];
    int tid = threadIdx.x;
    const char* wsrc = (const char*)pb1 + (size_t)(e * 2 + jh) * 73728;
#pragma unroll
    for (int i = 0; i < 9; ++i)
        GLOAD_LDS16(wsrc + i * 8192 + tid * 16, wlds + i * 8192 + tid * 16);

    int wv = tid >> 6, lane = tid & 63;
    int lrow = lane & 15, lgrp = lane >> 4;
    const int* tl = toks + e * N_TOK;
    const float* b1base = b1 + e * HID + jh * 192;
    float b1j[12];
#pragma unroll
    for (int jt = 0; jt < 12; ++jt) b1j[jt] = b1base[jt * 16 + lrow];

    int L  = (ntiles + 31) >> 5;
    int t0 = rep * L;
    int t1 = min(t0 + L, ntiles);
    __syncthreads();   // stage drained (syncthreads waits vmcnt)

    for (int t = t0 + wv; t < t1; t += 8) {
        int base = t * 16;
        int tok = tl[min(base + lrow, cnt - 1)];
        const char* xr = (const char*)x + (size_t)tok * 768 + lgrp * 32;
        short8 a[6];
#pragma unroll
        for (int kt = 0; kt < 6; ++kt) {
            float4 v0 = *(const float4*)(xr + kt * 128);
            float4 v1 = *(const float4*)(xr + kt * 128 + 16);
            short8 s;
            s[0] = f2bf(v0.x); s[1] = f2bf(v0.y); s[2] = f2bf(v0.z); s[3] = f2bf(v0.w);
            s[4] = f2bf(v1.x); s[5] = f2bf(v1.y); s[6] = f2bf(v1.z); s[7] = f2bf(v1.w);
            a[kt] = s;
        }

        f32x4 acc[12];
#pragma unroll
        for (int j = 0; j < 12; ++j) acc[j] = (f32x4){0.f, 0.f, 0.f, 0.f};
#pragma unroll
        for (int kt = 0; kt < 6; ++kt)
#pragma unroll
            for (int jt = 0; jt < 12; ++jt) {
                short8 bb = *(const short8*)(wlds + ((kt * 12 + jt) * 64 + lane) * 16);
                acc[jt] = __builtin_amdgcn_mfma_f32_16x16x32_bf16(a[kt], bb, acc[jt], 0, 0, 0);
            }

#pragma unroll
        for (int rr = 0; rr < 4; ++rr) {
            int r = base + lgrp * 4 + rr;
            if (r < cnt) {
                char* hrow = Hp + (size_t)(gbase + r) * 768 + jh * 384;
#pragma unroll
                for (int jt = 0; jt < 12; ++jt) {
                    float h = acc[jt][rr] + b1j[jt];
                    float g = 0.5f * h * (1.f + erff(h * 0.70710678118654752f));
                    *(short*)(hrow + (jt * 16 + lrow) * 2) = f2bf(g);
                }
            }
        }
    }
}

// ---------------------------------------------------------------------------
// Pass 2 (primary): slot[gbase+r][oh*96:+96] = gate * exp(y^T) with
// y^T = W2^T @ H^T : A = W2^T frags (LDS-persistent), B = H rows (contig 16B).
// D layout: col = token-in-tile, row = out -> per-lane float4 stores.
// grid 512: bid = rep(32)*16 + oh*8 + e
// ---------------------------------------------------------------------------
__global__ __launch_bounds__(512, 2) void yp_kernel(
    const char* __restrict__ Hp,
    const short* __restrict__ pa2, const float* __restrict__ b2,
    const int* __restrict__ counts, const float* __restrict__ gates,
    float* __restrict__ slot)
{
    int bid = blockIdx.x;
    int e   = bid & 7;
    int oh  = (bid >> 3) & 1;
    int rep = bid >> 4;
    int cnt = counts[e];
    int ntiles = (cnt + 15) >> 4;
    int gbase = 0;
#pragma unroll
    for (int i = 0; i < NEXP; ++i) gbase += (i < e) ? counts[i] : 0;

    __shared__ __align__(16) char wlds[73728];
    int tid = threadIdx.x;
    const char* wsrc = (const char*)pa2 + (size_t)(e * 2 + oh) * 73728;
#pragma unroll
    for (int i = 0; i < 9; ++i)
        GLOAD_LDS16(wsrc + i * 8192 + tid * 16, wlds + i * 8192 + tid * 16);

    int wv = tid >> 6, lane = tid & 63;
    int lrow = lane & 15, lgrp = lane >> 4;
    const float* gl = gates + e * N_TOK;
    f32x4 b2v[6];
#pragma unroll
    for (int m = 0; m < 6; ++m)
        b2v[m] = *(const f32x4*)(b2 + e * DIM + oh * 96 + m * 16 + lgrp * 4);

    int L  = (ntiles + 31) >> 5;
    int t0 = rep * L;
    int t1 = min(t0 + L, ntiles);
    __syncthreads();

    for (int t = t0 + wv; t < t1; t += 8) {
        int base = t * 16;
        int nrow = min(base + lrow, cnt - 1);          // token row for B-frag col
        const char* hr = Hp + (size_t)(gbase + nrow) * 768 + lgrp * 16;
        short8 bfr[12];
#pragma unroll
        for (int kt = 0; kt < 12; ++kt) bfr[kt] = *(const short8*)(hr + kt * 64);

        f32x4 acc[6];
#pragma unroll
        for (int m = 0; m < 6; ++m) acc[m] = (f32x4){0.f, 0.f, 0.f, 0.f};
#pragma unroll
        for (int kt = 0; kt < 12; ++kt)
#pragma unroll
            for (int m = 0; m < 6; ++m) {
                short8 aa = *(const short8*)(wlds + ((kt * 6 + m) * 64 + lane) * 16);
                acc[m] = __builtin_amdgcn_mfma_f32_16x16x32_bf16(aa, bfr[kt], acc[m], 0, 0, 0);
            }

        int r = base + lrow;                            // this lane's token row
        if (r < cnt) {
            float g = gl[r];
            float* srow = slot + (size_t)(gbase + r) * DIM + oh * 96;
#pragma unroll
            for (int m = 0; m < 6; ++m) {
                float4 o;
                o.x = g * expf(acc[m][0] + b2v[m][0]);
                o.y = g * expf(acc[m][1] + b2v[m][1]);
                o.z = g * expf(acc[m][2] + b2v[m][2]);
                o.w = g * expf(acc[m][3] + b2v[m][3]);
                *(float4*)(srow + m * 16 + lgrp * 4) = o;
            }
        }
    }
}

// ---------------------------------------------------------------------------
// Pass 2 (fallback, small ws): full-out W2^T streamed from global, fp32 result
// written IN PLACE over the wave's own Hp rows (read-before-write, same wave).
// grid 512: bid = rep(64)*8 + e
// ---------------------------------------------------------------------------
__global__ __launch_bounds__(512) void yp_global_kernel(
    char* __restrict__ Hp,
    const short* __restrict__ pa2, const float* __restrict__ b2,
    const int* __restrict__ counts, const float* __restrict__ gates)
{
    int bid = blockIdx.x;
    int e   = bid & 7;
    int rep = bid >> 3;
    int cnt = counts[e];
    int ntiles = (cnt + 15) >> 4;
    int gbase = 0;
#pragma unroll
    for (int i = 0; i < NEXP; ++i) gbase += (i < e) ? counts[i] : 0;

    int tid = threadIdx.x;
    int wv = tid >> 6, lane = tid & 63;
    int lrow = lane & 15, lgrp = lane >> 4;
    const float* gl = gates + e * N_TOK;
    const short8* wbase = (const short8*)(pa2 + (size_t)e * 2 * 36864) + lane;

    f32x4 b2v[12];
#pragma unroll
    for (int m = 0; m < 12; ++m)
        b2v[m] = *(const f32x4*)(b2 + e * DIM + m * 16 + lgrp * 4);

    int L  = (ntiles + 63) >> 6;
    int t0 = rep * L;
    int t1 = min(t0 + L, ntiles);

    for (int t = t0 + wv; t < t1; t += 8) {
        int base = t * 16;
        int nrow = min(base + lrow, cnt - 1);
        const char* hr = Hp + (size_t)(gbase + nrow) * 768 + lgrp * 16;
        short8 bfr[12];
#pragma unroll
        for (int kt = 0; kt < 12; ++kt) bfr[kt] = *(const short8*)(hr + kt * 64);

        f32x4 acc[12];
#pragma unroll
        for (int m = 0; m < 12; ++m) acc[m] = (f32x4){0.f, 0.f, 0.f, 0.f};
#pragma unroll
        for (int kt = 0; kt < 12; ++kt)
#pragma unroll
            for (int m = 0; m < 12; ++m) {
                // pa2 layout: [e][oh][kt][mtl(6)][lane][8]; m = oh*6+mtl
                short8 aa = wbase[(((m / 6) * 12 + kt) * 6 + (m % 6)) * 64];
                acc[m] = __builtin_amdgcn_mfma_f32_16x16x32_bf16(aa, bfr[kt], acc[m], 0, 0, 0);
            }

        int r = base + lrow;
        if (r < cnt) {
            float g = gl[r];
            float* srow = (float*)(Hp + (size_t)(gbase + r) * 768);
#pragma unroll
            for (int m = 0; m < 12; ++m) {
                float4 o;
                o.x = g * expf(acc[m][0] + b2v[m][0]);
                o.y = g * expf(acc[m][1] + b2v[m][1]);
                o.z = g * expf(acc[m][2] + b2v[m][2]);
                o.w = g * expf(acc[m][3] + b2v[m][3]);
                *(float4*)(srow + m * 16 + lgrp * 4) = o;
            }
        }
    }
}

// ---------------------------------------------------------------------------
// out[t][:] = log(slot[g1(t)][:] + slot[g2(t)][:])
// ---------------------------------------------------------------------------
__global__ __launch_bounds__(256) void combine_kernel(
    const float* __restrict__ slot, const int* __restrict__ inv,
    const int* __restrict__ counts, float* __restrict__ out)
{
    __shared__ int rb[NEXP];
    int tid = threadIdx.x;
    if (tid < NEXP) {
        int s = 0;
        for (int i = 0; i < tid; ++i) s += counts[i];
        rb[tid] = s;
    }
    __syncthreads();

    int gid = blockIdx.x * 256 + tid;        // over N_TOK*48
    int t = gid / 48, q = gid - t * 48;
    int v1 = inv[2 * t], v2 = inv[2 * t + 1];
    int g1 = rb[v1 >> 17] + (v1 & 0x1FFFF);
    int g2 = rb[v2 >> 17] + (v2 & 0x1FFFF);
    float4 a = *(const float4*)(slot + (size_t)g1 * DIM + q * 4);
    float4 b = *(const float4*)(slot + (size_t)g2 * DIM + q * 4);
    float4 o;
    float c;
    c = a.x + b.x; o.x = logf(c == 0.f ? EPSV : c);
    c = a.y + b.y; o.y = logf(c == 0.f ? EPSV : c);
    c = a.z + b.z; o.z = logf(c == 0.f ? EPSV : c);
    c = a.w + b.w; o.w = logf(c == 0.f ? EPSV : c);
    *reinterpret_cast<float4*>(out + (size_t)t * DIM + q * 4) = o;
}

// ---------------------------------------------------------------------------
extern "C" void kernel_launch(void* const* d_in, const int* in_sizes, int n_in,
                              void* d_out, int out_size, void* d_ws, size_t ws_size,
                              hipStream_t stream) {
    const float* x   = (const float*)d_in[0];
    const float* emb = (const float*)d_in[1];
    const float* wg  = (const float*)d_in[2];
    const float* w1  = (const float*)d_in[3];
    const float* b1  = (const float*)d_in[4];
    const float* w2  = (const float*)d_in[5];
    const float* b2  = (const float*)d_in[6];
    float* out = (float*)d_out;

    char* ws = (char*)d_ws;
    size_t off = 0;
    auto alloc = [&](size_t n) { size_t p = off; off = (off + n + 255) & ~(size_t)255; return p; };
    int*   counts = (int*)  (ws + alloc(256));
    int*   toks   = (int*)  (ws + alloc((size_t)NEXP * N_TOK * 4));
    float* gates  = (float*)(ws + alloc((size_t)NEXP * N_TOK * 4));
    int*   inv    = (int*)  (ws + alloc((size_t)2 * N_TOK * 4));
    short* pb1    = (short*)(ws + alloc((size_t)NEXP * DIM * HID * 2));
    short* pa2    = (short*)(ws + alloc((size_t)NEXP * HID * DIM * 2));
    char*  Hp     = (char*) (ws + alloc((size_t)2 * N_TOK * 768));   // bf16 H rows / fp32 slot rows
    size_t sloff  = alloc((size_t)2 * N_TOK * DIM * 4);              // separate fp32 slot
    float* slot   = (float*)(ws + sloff);
    bool split_y  = (ws_size >= off);

    hipMemsetAsync(counts, 0, NEXP * sizeof(int), stream);

    pack_kernel<<<(2 * 73728) / 256, 256, 0, stream>>>(w1, w2, pb1, pa2);
    gate_kernel<<<N_TOK / 64, 256, 0, stream>>>(x, emb, wg, counts, toks, gates, inv);
    hp_kernel<<<512, 512, 0, stream>>>(x, pb1, b1, counts, toks, Hp);

    if (split_y) {
        yp_kernel<<<512, 512, 0, stream>>>(Hp, pa2, b2, counts, gates, slot);
        combine_kernel<<<(N_TOK * 48) / 256, 256, 0, stream>>>(slot, inv, counts, out);
    } else {
        yp_global_kernel<<<512, 512, 0, stream>>>(Hp, pa2, b2, counts, gates);
        combine_kernel<<<(N_TOK * 48) / 256, 256, 0, stream>>>((const float*)Hp, inv, counts, out);
    }
}